// Round 2
// 4236.112 us; speedup vs baseline: 1.1628x; 1.1628x over previous
//
#include <hip/hip_runtime.h>
#include <hip/hip_bf16.h>
#include <cstdint>
#include <cstddef>

// ---------------------------------------------------------------------------
// Model dims: NL=32, D=256, DI=512, N=16, R=16, K=4, V=4096, FF=1024, B=32, L=256
// R5: deadlock-free SSM fusion (R4's inter-block spin-wait removed — probable
//   co-residency hang: 256 blocks at exactly 1 block/CU = zero slack).
//   3 dispatches/layer, dispatch boundary = the chunk-prefix barrier:
//     gemm_bt<0> (in_proj)
//     convscan1_k : conv+silu -> sXC (LDS only) ; x_proj MFMA -> DBC (global,
//                   L2-local) ; scan pass1 -> PART/PROD.   XC buffer GONE.
//     scan2out_k  : prefix combine ; conv recomputed per-column (rolling
//                   3-tap window, regs) ; recurrence+gate -> sY (LDS) ;
//                   out_proj GEMM + residual + LN fused.   Y buffer GONE.
//   No kernel has any cross-block dependency. 101 dispatches total.
// ---------------------------------------------------------------------------

typedef __bf16 v8bf __attribute__((ext_vector_type(8)));
typedef float  v4f  __attribute__((ext_vector_type(4)));

__device__ __forceinline__ void async_copy16(const void* g, void* l) {
  __builtin_amdgcn_global_load_lds((const __attribute__((address_space(1))) void*)g,
                                   (__attribute__((address_space(3))) void*)l, 16, 0, 0);
}

__device__ __forceinline__ float bf(__bf16 v) { return (float)v; }

// ---------------- workspace layout (bytes) ---------------------------------
constexpr size_t OFF_WIN  = 0;           // bf16 32*1024*256
constexpr size_t OFF_WXP  = 16777216;    // bf16 32*48*512
constexpr size_t OFF_WOUT = 18350080;    // bf16 32*256*512
constexpr size_t OFF_WW1  = 26738688;    // bf16 1024*256
constexpr size_t OFF_WW2  = 27262976;    // bf16 4096*1024
constexpr size_t OFF_X    = 35651584;    // f32  8192*256   residual stream
constexpr size_t OFF_H    = 44040192;    // bf16 8192*256   LN output
constexpr size_t OFF_XZ   = 48234496;    // bf16 8192*1024  in_proj out
constexpr size_t OFF_DBC  = 73400320;    // f32  8192*48    x_proj out
constexpr size_t OFF_PART = 83361792;    // f32  7*32*512*16 (alias: XB head in)
constexpr size_t OFF_PROD = 91750400;    // f32  same        (alias: HH head mid)
// HH extends to 108,527,616 B (proven available in R2)

// ---------------- batched f32 -> bf16 weight conversion --------------------
__global__ __launch_bounds__(256)
void f2b_multi(const float* __restrict__ s0, const float* __restrict__ s1,
               const float* __restrict__ s2, const float* __restrict__ s3,
               const float* __restrict__ s4, char* __restrict__ ws) {
  size_t i = (size_t)blockIdx.x * 256 + threadIdx.x;
  if (i < 8388608) { ((__bf16*)(ws + OFF_WIN))[i] = (__bf16)s0[i]; return; }
  i -= 8388608;
  if (i < 786432)  { ((__bf16*)(ws + OFF_WXP))[i] = (__bf16)s1[i]; return; }
  i -= 786432;
  if (i < 4194304) { ((__bf16*)(ws + OFF_WOUT))[i] = (__bf16)s2[i]; return; }
  i -= 4194304;
  if (i < 262144)  { ((__bf16*)(ws + OFF_WW1))[i] = (__bf16)s3[i]; return; }
  i -= 262144;
  ((__bf16*)(ws + OFF_WW2))[i] = (__bf16)s4[i];
}

__global__ __launch_bounds__(256) void f2b_k(const float* __restrict__ X,
                                             __bf16* __restrict__ O) {
  size_t i = (size_t)blockIdx.x * 256 + threadIdx.x;
  O[i] = (__bf16)X[i];
}

// ---------------- embed + layer-0 LN ---------------------------------------
__global__ __launch_bounds__(256)
void embed_ln_k(const int* __restrict__ tok, const float* __restrict__ emb,
                const float* __restrict__ w, const float* __restrict__ b,
                float* __restrict__ X, __bf16* __restrict__ H) {
  int row = blockIdx.x;
  int t   = threadIdx.x;
  float v = emb[(size_t)tok[row] * 256 + t];
  X[(size_t)row * 256 + t] = v;
  float s = v, q = v * v;
  #pragma unroll
  for (int o = 32; o > 0; o >>= 1) { s += __shfl_xor(s, o); q += __shfl_xor(q, o); }
  __shared__ float ss[4], qq[4];
  int wv = t >> 6;
  if ((t & 63) == 0) { ss[wv] = s; qq[wv] = q; }
  __syncthreads();
  s = ss[0] + ss[1] + ss[2] + ss[3];
  q = qq[0] + qq[1] + qq[2] + qq[3];
  float mu  = s * (1.f / 256.f);
  float var = q * (1.f / 256.f) - mu * mu;
  float r   = rsqrtf(var + 1e-5f);
  H[(size_t)row * 256 + t] = (__bf16)((v - mu) * r * w[t] + b[t]);
}

// ---------------- generic MFMA bf16 GEMM: C(M,N) = A(M,K) @ W(N,K)^T -------
// BM=BN=128, BK=32, 256 threads. EPI: 0 = bf16; 1 = +bias relu bf16; 2 = +bias f32
template <int EPI>
__global__ __launch_bounds__(256, 2)
void gemm_bt(const __bf16* __restrict__ A, const __bf16* __restrict__ W,
             void* outp, const float* __restrict__ bias, int M, int N, int K) {
  __shared__ __align__(16) __bf16 sA[128 * 32];
  __shared__ __align__(16) __bf16 sB[128 * 32];
  const int tid  = threadIdx.x;
  const int bm0  = blockIdx.y << 7;
  const int bn0  = blockIdx.x << 7;
  const int lane = tid & 63;
  const int wv   = tid >> 6;
  const int wm   = (wv >> 1) << 6;
  const int wn   = (wv & 1) << 6;
  const int lr   = lane & 15;
  const int lk   = lane >> 4;

  v4f acc[4][4] = {};

  const int r0 = tid >> 2;
  const int c0 = (tid & 3) << 3;
  const int wbase = (tid & ~63) << 3;

  const __bf16* gA0 = A + (size_t)(bm0 + r0) * K + c0;
  const __bf16* gA1 = A + (size_t)(bm0 + 64 + r0) * K + c0;
  const __bf16* gB0 = W + (size_t)(bn0 + r0) * K + c0;
  const __bf16* gB1 = W + (size_t)(bn0 + 64 + r0) * K + c0;

  for (int kk = 0; kk < K; kk += 32) {
    async_copy16(gA0 + kk, sA + wbase);
    async_copy16(gA1 + kk, sA + 2048 + wbase);
    async_copy16(gB0 + kk, sB + wbase);
    async_copy16(gB1 + kk, sB + 2048 + wbase);
    __syncthreads();
    v8bf af[4], bfr[4];
    #pragma unroll
    for (int i = 0; i < 4; ++i)
      af[i] = *(const v8bf*)(sA + ((wm + i * 16 + lr) << 5) + (lk << 3));
    #pragma unroll
    for (int j = 0; j < 4; ++j)
      bfr[j] = *(const v8bf*)(sB + ((wn + j * 16 + lr) << 5) + (lk << 3));
    #pragma unroll
    for (int i = 0; i < 4; ++i)
      #pragma unroll
      for (int j = 0; j < 4; ++j)
        acc[i][j] = __builtin_amdgcn_mfma_f32_16x16x32_bf16(af[i], bfr[j], acc[i][j], 0, 0, 0);
    __syncthreads();
  }

  #pragma unroll
  for (int i = 0; i < 4; ++i) {
    #pragma unroll
    for (int j = 0; j < 4; ++j) {
      int gc = bn0 + wn + j * 16 + lr;
      #pragma unroll
      for (int v = 0; v < 4; ++v) {
        int gr = bm0 + wm + i * 16 + (lk << 2) + v;
        float val = acc[i][j][v];
        size_t idx = (size_t)gr * N + gc;
        if (EPI == 0) {
          ((__bf16*)outp)[idx] = (__bf16)val;
        } else if (EPI == 1) {
          val += bias[gc]; val = fmaxf(val, 0.f);
          ((__bf16*)outp)[idx] = (__bf16)val;
        } else {
          ((float*)outp)[idx] = val + bias[gc];
        }
      }
    }
  }
}

// ---------------- K2: conv+silu + x_proj + scan pass1 ----------------------
// Grid 256 blocks = chunk c (bid>>5) x batch b (bid&31); 512 threads.
// sXC (swizzled, LDS-only) -> x_proj MFMA -> sDBC -> DBC global (L2-local,
// same-XCD consumer) ; scan pass1 (c<7) -> PART/PROD. No cross-block deps.
__global__ __launch_bounds__(512, 2)
void convscan1_k(const __bf16* __restrict__ XZ,
                 const float* __restrict__ cw, const float* __restrict__ cb,
                 const __bf16* __restrict__ Wxp,
                 const float* __restrict__ dtw, const float* __restrict__ dtb,
                 const float* __restrict__ Alog,
                 float* __restrict__ DBC,
                 float* __restrict__ PART, float* __restrict__ PROD) {
  __shared__ __align__(16) __bf16 sXC[32 * 512];   // 32KB, XOR-swizzled
  __shared__ __align__(16) float  sDBC[32 * 48];   // 6KB
  const int tid = threadIdx.x;
  const int c   = blockIdx.x >> 5;
  const int b   = blockIdx.x & 31;
  const int bl0 = b * 256 + c * 32;

  // -- Phase A: depthwise causal conv + SiLU into LDS (swizzled 16B blocks)
  {
    const int r  = tid >> 4;          // row 0..31
    const int ec = tid & 15;
    #pragma unroll
    for (int j = 0; j < 4; ++j) {
      const int e = (ec << 3) + (j << 7);   // 8-wide channel chunk
      v4f cw4[8];
      #pragma unroll
      for (int jj = 0; jj < 8; ++jj) cw4[jj] = *(const v4f*)(cw + (size_t)(e + jj) * 4);
      float a[8];
      #pragma unroll
      for (int jj = 0; jj < 8; ++jj) a[jj] = cb[e + jj];
      #pragma unroll
      for (int k = 0; k < 4; ++k) {
        if (c > 0 || r + k >= 3) {          // seq pos c*32+r; tap valid iff pos+k>=3
          const v8bf xv = *(const v8bf*)(XZ + (size_t)(bl0 + r + k - 3) * 1024 + e);
          #pragma unroll
          for (int jj = 0; jj < 8; ++jj) a[jj] += bf(xv[jj]) * cw4[jj][k];
        }
      }
      v8bf outv;
      #pragma unroll
      for (int jj = 0; jj < 8; ++jj) {
        float s = a[jj] / (1.f + __expf(-a[jj]));
        outv[jj] = (__bf16)s;
      }
      const int cbk = (e >> 3) ^ (r & 7);   // XOR-swizzle 16B blocks within row
      *(v8bf*)(sXC + r * 512 + (cbk << 3)) = outv;
    }
  }
  __syncthreads();

  // -- Phase B: sDBC(32x48) = xc @ Wxp^T (3 waves MFMA; Wxp from L2)
  if (tid < 192) {
    const int w = tid >> 6, lane = tid & 63, lr = lane & 15, lk = lane >> 4;
    v4f acc[2] = {};
    for (int kk = 0; kk < 512; kk += 32) {
      const v8bf bfr = *(const v8bf*)(Wxp + (size_t)(w * 16 + lr) * 512 + kk + (lk << 3));
      #pragma unroll
      for (int i = 0; i < 2; ++i) {
        const int row = i * 16 + lr;
        const int cbk = (((kk >> 3) + lk) ^ (row & 7));
        const v8bf af = *(const v8bf*)(sXC + row * 512 + (cbk << 3));
        acc[i] = __builtin_amdgcn_mfma_f32_16x16x32_bf16(af, bfr, acc[i], 0, 0, 0);
      }
    }
    const int gc = w * 16 + lr;
    #pragma unroll
    for (int i = 0; i < 2; ++i)
      #pragma unroll
      for (int v = 0; v < 4; ++v)
        sDBC[(i * 16 + (lk << 2) + v) * 48 + gc] = acc[i][v];
  }
  __syncthreads();

  // -- DBC writeback (6KB; consumed by scan2out_k on the same XCD -> L2 hit)
  if (tid < 384)
    *(v4f*)(DBC + (size_t)bl0 * 48 + tid * 4) = *(const v4f*)(sDBC + tid * 4);

  // -- Phase C: scan pass1 -> per-chunk (part, prod) for chunks 0..6
  if (c < 7) {
    const int e = tid;
    float Arow2[16], Wdt[16];
    #pragma unroll
    for (int n = 0; n < 16; ++n) {
      Arow2[n] = -1.4426950408889634f * __expf(Alog[(size_t)e * 16 + n]);  // exp(x)=exp2(x*log2e)
      Wdt[n]   = dtw[(size_t)e * 16 + n];
    }
    const float bias = dtb[e];
    float part[16], prod[16];
    #pragma unroll
    for (int n = 0; n < 16; ++n) { part[n] = 0.f; prod[n] = 1.f; }
    for (int tt = 0; tt < 32; ++tt) {
      const v4f* dp = (const v4f*)(sDBC + tt * 48);   // wave-uniform broadcast
      v4f d0 = dp[0], d1 = dp[1], d2 = dp[2], d3 = dp[3];
      v4f bv0 = dp[4], bv1 = dp[5], bv2 = dp[6], bv3 = dp[7];
      float dtv = bias;
      #pragma unroll
      for (int r = 0; r < 4; ++r)
        dtv += d0[r] * Wdt[r] + d1[r] * Wdt[r + 4] + d2[r] * Wdt[r + 8] + d3[r] * Wdt[r + 12];
      dtv = (dtv > 20.f) ? dtv : log1pf(__expf(dtv));
      const float x = bf(sXC[tt * 512 + (((e >> 3) ^ (tt & 7)) << 3) + (e & 7)]);
      const float dtx = dtv * x;
      float Bv[16];
      #pragma unroll
      for (int r = 0; r < 4; ++r) { Bv[r] = bv0[r]; Bv[r+4] = bv1[r]; Bv[r+8] = bv2[r]; Bv[r+12] = bv3[r]; }
      #pragma unroll
      for (int n = 0; n < 16; ++n) {
        const float dA = exp2f(dtv * Arow2[n]);
        part[n] = part[n] * dA + dtx * Bv[n];
        prod[n] *= dA;
      }
    }
    const size_t o = (((size_t)c * 32 + b) * 512 + e) * 16;
    #pragma unroll
    for (int rq = 0; rq < 4; ++rq) {
      v4f p, q;
      #pragma unroll
      for (int v = 0; v < 4; ++v) { p[v] = part[rq * 4 + v]; q[v] = prod[rq * 4 + v]; }
      *(v4f*)(PART + o + rq * 4) = p;
      *(v4f*)(PROD + o + rq * 4) = q;
    }
  }
}

// ---------------- K3: prefix + scan pass2 + gate + out_proj + resid + LN ---
// Grid 256 blocks = (c,b); 512 threads. Conv recomputed per-column (3-tap
// rolling window in regs, no XC buffer). Y kept in LDS (padded [32][520]),
// then out_proj GEMM 32x256 (8 waves) + residual + LN fused.
__global__ __launch_bounds__(512, 2)
void scan2out_k(const __bf16* __restrict__ XZ,
                const float* __restrict__ cw, const float* __restrict__ cb,
                const float* __restrict__ DBC,
                const float* __restrict__ dtw, const float* __restrict__ dtb,
                const float* __restrict__ Alog, const float* __restrict__ Dskip,
                const float* __restrict__ PART, const float* __restrict__ PROD,
                const __bf16* __restrict__ Wout,
                const float* __restrict__ lnw, const float* __restrict__ lnb,
                float* __restrict__ X, __bf16* __restrict__ H) {
  __shared__ __align__(16) __bf16 sY[32 * 520];   // 33.3KB, pad breaks bank stride
  __shared__ __align__(16) __bf16 sB[256 * 32];   // 16KB Wout k-tile
  __shared__ float sSum[4][32], sSq[4][32];
  const int tid = threadIdx.x;
  const int c   = blockIdx.x >> 5;
  const int b   = blockIdx.x & 31;
  const int bl0 = b * 256 + c * 32;
  const int e   = tid;

  // per-channel constants
  float Arow2[16], Wdt[16];
  #pragma unroll
  for (int n = 0; n < 16; ++n) {
    Arow2[n] = -1.4426950408889634f * __expf(Alog[(size_t)e * 16 + n]);
    Wdt[n]   = dtw[(size_t)e * 16 + n];
  }
  const float bias = dtb[e];
  const float Dsk  = Dskip[e];
  const v4f   cwv  = *(const v4f*)(cw + (size_t)e * 4);
  const float cbe  = cb[e];

  // chunk-prefix combine (PART/PROD written by previous dispatch -> visible)
  float h[16];
  #pragma unroll
  for (int n = 0; n < 16; ++n) h[n] = 0.f;
  for (int cc = 0; cc < c; ++cc) {
    const size_t o = (((size_t)cc * 32 + b) * 512 + e) * 16;
    #pragma unroll
    for (int rq = 0; rq < 4; ++rq) {
      const v4f p = *(const v4f*)(PART + o + rq * 4);
      const v4f q = *(const v4f*)(PROD + o + rq * 4);
      #pragma unroll
      for (int v = 0; v < 4; ++v) h[rq * 4 + v] = q[v] * h[rq * 4 + v] + p[v];
    }
  }

  // conv rolling window halo (seq positions c*32-3..-1; zero-pad at c==0)
  float w0 = 0.f, w1 = 0.f, w2 = 0.f;
  if (c > 0) {
    w0 = bf(XZ[(size_t)(bl0 - 3) * 1024 + e]);
    w1 = bf(XZ[(size_t)(bl0 - 2) * 1024 + e]);
    w2 = bf(XZ[(size_t)(bl0 - 1) * 1024 + e]);
  }

  // in-chunk recurrence + C-dot + skip + gate -> sY
  #pragma unroll 2
  for (int tt = 0; tt < 32; ++tt) {
    const float xt = bf(XZ[(size_t)(bl0 + tt) * 1024 + e]);
    float a = cbe + w0 * cwv[0] + w1 * cwv[1] + w2 * cwv[2] + xt * cwv[3];
    const float x = a / (1.f + __expf(-a));      // f32 conv+silu (no bf16 trip)
    w0 = w1; w1 = w2; w2 = xt;
    const float* dpf = DBC + (size_t)(bl0 + tt) * 48;
    const v4f* dp = (const v4f*)dpf;
    v4f d0 = dp[0], d1 = dp[1], d2 = dp[2], d3 = dp[3];
    v4f bv0 = dp[4], bv1 = dp[5], bv2 = dp[6], bv3 = dp[7];
    v4f cv0 = dp[8], cv1 = dp[9], cv2 = dp[10], cv3 = dp[11];
    float dtv = bias;
    #pragma unroll
    for (int r = 0; r < 4; ++r)
      dtv += d0[r] * Wdt[r] + d1[r] * Wdt[r + 4] + d2[r] * Wdt[r + 8] + d3[r] * Wdt[r + 12];
    dtv = (dtv > 20.f) ? dtv : log1pf(__expf(dtv));
    const float dtx = dtv * x;
    float Bv[16], Cv[16];
    #pragma unroll
    for (int r = 0; r < 4; ++r) {
      Bv[r] = bv0[r]; Bv[r+4] = bv1[r]; Bv[r+8] = bv2[r]; Bv[r+12] = bv3[r];
      Cv[r] = cv0[r]; Cv[r+4] = cv1[r]; Cv[r+8] = cv2[r]; Cv[r+12] = cv3[r];
    }
    float y = 0.f;
    #pragma unroll
    for (int n = 0; n < 16; ++n) {
      const float dA = exp2f(dtv * Arow2[n]);
      h[n] = h[n] * dA + dtx * Bv[n];
      y += h[n] * Cv[n];
    }
    const float z  = bf(XZ[(size_t)(bl0 + tt) * 1024 + 512 + e]);
    const float sg = z / (1.f + __expf(-z));
    sY[tt * 520 + e] = (__bf16)((y + x * Dsk) * sg);
  }
  __syncthreads();

  // out_proj GEMM: C(32x256) = sY(32x512) @ Wout(256x512)^T, 8 waves
  const int w = tid >> 6, lane = tid & 63, lr = lane & 15, lk = lane >> 4;
  const int wm = (w & 1) << 4;         // row group 0/16
  const int wn = (w >> 1) << 6;        // col group 0/64/128/192
  v4f acc[4] = {};
  for (int kk = 0; kk < 512; kk += 32) {
    // stage Wout k-tile 256x32 (1024 16B chunks, 2 per thread)
    async_copy16(Wout + (size_t)(tid >> 2) * 512 + ((tid & 3) << 3) + kk,
                 sB + ((tid & ~63) << 3));
    async_copy16(Wout + (size_t)(128 + (tid >> 2)) * 512 + ((tid & 3) << 3) + kk,
                 sB + 4096 + ((tid & ~63) << 3));
    __syncthreads();
    const v8bf af = *(const v8bf*)(sY + (wm + lr) * 520 + kk + (lk << 3));
    #pragma unroll
    for (int j = 0; j < 4; ++j) {
      const v8bf bfr = *(const v8bf*)(sB + ((wn + j * 16 + lr) << 5) + (lk << 3));
      acc[j] = __builtin_amdgcn_mfma_f32_16x16x32_bf16(af, bfr, acc[j], 0, 0, 0);
    }
    __syncthreads();
  }

  // residual add + per-row LN stats
  float s2[4], q2[4];
  #pragma unroll
  for (int v = 0; v < 4; ++v) {
    const int gr = bl0 + wm + (lk << 2) + v;
    float s = 0.f, q = 0.f;
    #pragma unroll
    for (int j = 0; j < 4; ++j) {
      const int gc = wn + j * 16 + lr;
      float val = X[(size_t)gr * 256 + gc] + acc[j][v];
      acc[j][v] = val;
      s += val; q += val * val;
    }
    #pragma unroll
    for (int o = 8; o > 0; o >>= 1) { s += __shfl_xor(s, o); q += __shfl_xor(q, o); }
    s2[v] = s; q2[v] = q;
  }
  if (lr == 0) {
    #pragma unroll
    for (int v = 0; v < 4; ++v) {
      const int row = wm + (lk << 2) + v;
      sSum[w >> 1][row] = s2[v];
      sSq[w >> 1][row]  = q2[v];
    }
  }
  __syncthreads();
  #pragma unroll
  for (int v = 0; v < 4; ++v) {
    const int row = wm + (lk << 2) + v;
    const float S = sSum[0][row] + sSum[1][row] + sSum[2][row] + sSum[3][row];
    const float Q = sSq[0][row]  + sSq[1][row]  + sSq[2][row]  + sSq[3][row];
    const float mu  = S * (1.f / 256.f);
    const float var = Q * (1.f / 256.f) - mu * mu;
    const float rinv = rsqrtf(var + 1e-5f);
    const int gr = bl0 + row;
    #pragma unroll
    for (int j = 0; j < 4; ++j) {
      const int gc = wn + j * 16 + lr;
      const float val = acc[j][v];
      X[(size_t)gr * 256 + gc] = val;
      H[(size_t)gr * 256 + gc] = (__bf16)((val - mu) * rinv * lnw[gc] + lnb[gc]);
    }
  }
}

extern "C" void kernel_launch(void* const* d_in, const int* in_sizes, int n_in,
                              void* d_out, int out_size, void* d_ws, size_t ws_size,
                              hipStream_t stream) {
  const int*   tok  = (const int*)d_in[0];
  const float* emb  = (const float*)d_in[1];
  const float* lnw  = (const float*)d_in[2];
  const float* lnb  = (const float*)d_in[3];
  const float* inw  = (const float*)d_in[4];
  const float* cw   = (const float*)d_in[5];
  const float* cb   = (const float*)d_in[6];
  const float* xpw  = (const float*)d_in[7];
  const float* dtw  = (const float*)d_in[8];
  const float* dtb  = (const float*)d_in[9];
  const float* alog = (const float*)d_in[10];
  const float* dsk  = (const float*)d_in[11];
  const float* outw = (const float*)d_in[12];
  const float* W1   = (const float*)d_in[13];
  const float* b1   = (const float*)d_in[14];
  const float* W2   = (const float*)d_in[15];
  const float* b2   = (const float*)d_in[16];

  char* ws = (char*)d_ws;
  __bf16* WIN   = (__bf16*)(ws + OFF_WIN);
  __bf16* WXP   = (__bf16*)(ws + OFF_WXP);
  __bf16* WOUT  = (__bf16*)(ws + OFF_WOUT);
  __bf16* WW1   = (__bf16*)(ws + OFF_WW1);
  __bf16* WW2   = (__bf16*)(ws + OFF_WW2);
  float*  X     = (float*)(ws + OFF_X);
  __bf16* H     = (__bf16*)(ws + OFF_H);
  __bf16* XZ    = (__bf16*)(ws + OFF_XZ);
  float*  DBC   = (float*)(ws + OFF_DBC);
  float*  PART  = (float*)(ws + OFF_PART);
  float*  PROD  = (float*)(ws + OFF_PROD);
  __bf16* XB    = (__bf16*)(ws + OFF_PART);   // head-phase aliases
  __bf16* HH    = (__bf16*)(ws + OFF_PROD);

  f2b_multi<<<69632, 256, 0, stream>>>(inw, xpw, outw, W1, W2, ws);
  embed_ln_k<<<8192, 256, 0, stream>>>(tok, emb, lnw, lnb, X, H);

  for (int l = 0; l < 32; ++l) {
    const __bf16* inw_l  = WIN  + (size_t)l * 1024 * 256;
    const float*  cw_l   = cw   + (size_t)l * 512 * 4;
    const float*  cb_l   = cb   + (size_t)l * 512;
    const __bf16* xpw_l  = WXP  + (size_t)l * 48 * 512;
    const float*  dtw_l  = dtw  + (size_t)l * 512 * 16;
    const float*  dtb_l  = dtb  + (size_t)l * 512;
    const float*  alog_l = alog + (size_t)l * 512 * 16;
    const float*  dsk_l  = dsk  + (size_t)l * 512;
    const __bf16* outw_l = WOUT + (size_t)l * 256 * 512;
    const int lnx = (l + 1 < 32) ? l + 1 : 31;   // next layer's LN (unused for l=31)

    gemm_bt<0><<<dim3(8, 64), 256, 0, stream>>>(H, inw_l, XZ, nullptr, 8192, 1024, 256);
    convscan1_k<<<256, 512, 0, stream>>>(XZ, cw_l, cb_l, xpw_l, dtw_l, dtb_l,
                                         alog_l, DBC, PART, PROD);
    scan2out_k<<<256, 512, 0, stream>>>(XZ, cw_l, cb_l, DBC, dtw_l, dtb_l,
                                        alog_l, dsk_l, PART, PROD, outw_l,
                                        lnw + (size_t)lnx * 256,
                                        lnb + (size_t)lnx * 256, X, H);
  }

  f2b_k<<<8192, 256, 0, stream>>>(X, XB);
  gemm_bt<1><<<dim3(8, 64), 256, 0, stream>>>(XB, WW1, HH, b1, 8192, 1024, 256);
  gemm_bt<2><<<dim3(32, 64), 256, 0, stream>>>(HH, WW2, (float*)d_out, b2, 8192, 4096, 1024);
}